// Round 10
// baseline (111.693 us; speedup 1.0000x reference)
//
#include <hip/hip_runtime.h>
#include <math.h>

#define D   128
#define LQ  256
#define KCQ 9
#define BQ  8
#define TQ  4096
#define RISK_DELTA 2e-5f
#define WCAP 16384

// ---------------- pk1: T2 = Wk^T@Wq, u = ctx_w^T@bias_w^T, transposed f32 tables ----
__global__ void pk1(const float* __restrict__ wk, const float* __restrict__ wq,
                    const float* __restrict__ ctx_w, const float* __restrict__ bias_w,
                    const float* __restrict__ conv_w, const float* __restrict__ val_b,
                    const float* __restrict__ lag_embed,
                    double* __restrict__ T2, double* __restrict__ u, int* __restrict__ wcnt,
                    float* __restrict__ ctx_wT, float* __restrict__ wqT,
                    float* __restrict__ conv_wT, float* __restrict__ baseT) {
    int tid = threadIdx.x;
    int bid = blockIdx.x;
    if (bid < D) {
        int d = bid;
        if (tid < D) {
            double acc = 0.0;
            for (int j = 0; j < D; ++j)
                acc += (double)wk[j * D + d] * (double)wq[j * D + tid];
            T2[d * D + tid] = acc;
            ctx_wT[d * D + tid] = ctx_w[tid * D + d];
            wqT[d * D + tid]    = wq[tid * D + d];
            if (d < KCQ) conv_wT[d * D + tid] = conv_w[tid * KCQ + d];
        }
        baseT[d * LQ + tid] = __fadd_rn(val_b[d], lag_embed[(size_t)(tid + 1) * D + d]);
    } else if (bid == D) {
        if (tid < D) {
            double acc = 0.0;
            for (int dd = 0; dd < D; ++dd)
                acc += (double)bias_w[dd] * (double)ctx_w[dd * D + tid];
            u[tid] = acc;
        }
    } else {
        if (tid == 0) *wcnt = 0;
    }
}

__global__ void pk2(const double* __restrict__ T2, const float* __restrict__ ctx_w,
                    const float* __restrict__ conv_w, const float* __restrict__ conv_b,
                    const float* __restrict__ ctx_b,
                    double* __restrict__ g, double* __restrict__ c1) {
    __shared__ double row[D];
    int d = blockIdx.x, e = threadIdx.x;
    double acc = 0.0;
    for (int j = 0; j < D; ++j)
        acc += T2[d * D + j] * (double)ctx_w[j * D + e];
    row[e] = acc;
    __syncthreads();
    if (e < KCQ) {
        double a = 0.0;
        for (int q = 0; q < D; ++q) a += row[q] * (double)conv_w[q * KCQ + e];
        g[e * D + d] = a;           // tap-major: g[k][d]
    } else if (e == KCQ) {
        double a = 0.0;
        for (int q = 0; q < D; ++q) a += row[q] * (double)conv_b[q];
        for (int q = 0; q < D; ++q) a += T2[d * D + q] * (double)ctx_b[q];
        c1[d] = a;
    }
}

__global__ void pk3(const float* __restrict__ lag_embed, const float* __restrict__ val_b,
                    const float* __restrict__ val_w, const float* __restrict__ conv_w,
                    const float* __restrict__ conv_b, const float* __restrict__ ctx_b,
                    const float* __restrict__ bias_w, const float* __restrict__ bias_b,
                    const double* __restrict__ g, const double* __restrict__ c1,
                    const double* __restrict__ u,
                    double* __restrict__ gbT, double* __restrict__ cbv, double* __restrict__ cst) {
    int tid = threadIdx.x;
    if (blockIdx.x < LQ) {
        __shared__ double bl[D];
        int l = blockIdx.x;
        bl[tid] = (double)val_b[tid] + (double)lag_embed[(l + 1) * D + tid];
        __syncthreads();
        if (tid < KCQ) {
            double a = 0.0;
            for (int q = 0; q < D; ++q) a += bl[q] * g[tid * D + q];
            gbT[tid * LQ + l] = a;
        } else if (tid == KCQ) {
            double a = 0.0;
            for (int q = 0; q < D; ++q) a += bl[q] * c1[q];
            cbv[l] = a;
        }
    } else {
        if (tid < KCQ) {
            double a = 0.0, a2 = 0.0;
            for (int q = 0; q < D; ++q) a  += g[tid * D + q] * (double)val_w[q];
            for (int q = 0; q < D; ++q) a2 += u[q] * (double)conv_w[q * KCQ + tid];
            cst[tid]      = a;    // sk[k]
            cst[10 + tid] = a2;   // hk[k]
        } else if (tid == KCQ) {
            double a = 0.0, a2 = 0.0;
            for (int q = 0; q < D; ++q) a  += c1[q] * (double)val_w[q];
            for (int q = 0; q < D; ++q) a2 += u[q] * (double)conv_b[q];
            for (int q = 0; q < D; ++q) a2 += (double)bias_w[q] * (double)ctx_b[q];
            cst[9]  = a;                          // ssc
            cst[19] = a2 + (double)bias_b[0];     // hc (incl. bias_b)
        }
    }
}

// ---------------- main kernel: 32-lane groups, 2 rows/wave, 8 rows/block -----------
// Lane gl (0..31) of its group owns lags {gl*4..gl*4+3} and {128+gl*4..128+gl*4+3}.
// Per-lag FMA order identical to round 5 -> identical logits/decisions.
__global__ __launch_bounds__(256, 4) void lag_main(
    const float* __restrict__ x, const double* __restrict__ gbT,
    const double* __restrict__ cbv, const double* __restrict__ cst,
    float* __restrict__ muOut, float* __restrict__ wOut,
    int* __restrict__ wcnt, int* __restrict__ wlist) {
    __shared__ float sgb[KCQ * LQ];
    __shared__ float scb[LQ];
    __shared__ float sc[20];
    int tid = threadIdx.x;
    #pragma unroll
    for (int i = 0; i < KCQ; ++i) sgb[i * LQ + tid] = (float)gbT[i * LQ + tid];
    scb[tid] = (float)cbv[tid];
    if (tid < 20) sc[tid] = (float)cst[tid];
    __syncthreads();

    int wave = tid >> 6, lane = tid & 63;
    int grp = lane >> 5, gl = lane & 31;
    int row = blockIdx.x * 8 + wave * 2 + grp;
    int b = row >> 12;
    int t = row & (TQ - 1);
    const float* xb = x + b * TQ;

    float xw[KCQ];
    #pragma unroll
    for (int k = 0; k < KCQ; ++k) {
        int idx = t - 8 + k;
        xw[k] = (idx >= 0) ? xb[idx] : 0.f;
    }
    float s = sc[9], bias = sc[19];
    #pragma unroll
    for (int k = 0; k < KCQ; ++k) {
        s    = fmaf(sc[k],      xw[k], s);
        bias = fmaf(sc[10 + k], xw[k], bias);
    }

    int l0 = gl * 4;
    float xlag[8];
    #pragma unroll
    for (int i = 0; i < 4; ++i) {
        int idxA = t - 1 - (l0 + i);
        int idxB = t - 1 - (128 + l0 + i);
        xlag[i]     = (idxA >= 0) ? xb[idxA] : 0.f;
        xlag[4 + i] = (idxB >= 0) ? xb[idxB] : 0.f;
    }

    float lg[8];
    {
        float4 cA = *reinterpret_cast<const float4*>(&scb[l0]);
        float4 cB = *reinterpret_cast<const float4*>(&scb[128 + l0]);
        lg[0] = cA.x; lg[1] = cA.y; lg[2] = cA.z; lg[3] = cA.w;
        lg[4] = cB.x; lg[5] = cB.y; lg[6] = cB.z; lg[7] = cB.w;
    }
    #pragma unroll
    for (int k = 0; k < KCQ; ++k) {
        float xk = xw[k];
        float4 gA = *reinterpret_cast<const float4*>(&sgb[k * LQ + l0]);
        float4 gB = *reinterpret_cast<const float4*>(&sgb[k * LQ + 128 + l0]);
        lg[0] = fmaf(gA.x, xk, lg[0]);
        lg[1] = fmaf(gA.y, xk, lg[1]);
        lg[2] = fmaf(gA.z, xk, lg[2]);
        lg[3] = fmaf(gA.w, xk, lg[3]);
        lg[4] = fmaf(gB.x, xk, lg[4]);
        lg[5] = fmaf(gB.y, xk, lg[5]);
        lg[6] = fmaf(gB.z, xk, lg[6]);
        lg[7] = fmaf(gB.w, xk, lg[7]);
    }
    #pragma unroll
    for (int j = 0; j < 8; ++j) lg[j] = fmaf(xlag[j], s, lg[j]);

    // top-9 within the 32-lane group: mx (1st), thr (8th), v9 (9th)
    const float NEG_INF = -__builtin_inff();
    float wl[8];
    #pragma unroll
    for (int j = 0; j < 8; ++j) wl[j] = lg[j];
    unsigned long long gmask = 0xFFFFFFFFull << (grp * 32);
    float mx = 0.f, thr = 0.f, v9 = 0.f;
    #pragma unroll
    for (int it = 0; it < 9; ++it) {
        float a0 = fmaxf(wl[0], wl[1]), a1 = fmaxf(wl[2], wl[3]);
        float a2 = fmaxf(wl[4], wl[5]), a3 = fmaxf(wl[6], wl[7]);
        float lm = fmaxf(fmaxf(a0, a1), fmaxf(a2, a3));
        float m = lm;
        m = fmaxf(m, __shfl_xor(m, 1, 64));
        m = fmaxf(m, __shfl_xor(m, 2, 64));
        m = fmaxf(m, __shfl_xor(m, 4, 64));
        m = fmaxf(m, __shfl_xor(m, 8, 64));
        m = fmaxf(m, __shfl_xor(m, 16, 64));
        if (it == 0) mx = m;
        if (it == 7) thr = m;
        if (it == 8) v9 = m;
        if (it < 8) {
            unsigned long long ball = __ballot(lm == m) & gmask;
            int leader = __ffsll(ball) - 1;
            if (lane == leader) {
                if (wl[0] == m)      wl[0] = NEG_INF;
                else if (wl[1] == m) wl[1] = NEG_INF;
                else if (wl[2] == m) wl[2] = NEG_INF;
                else if (wl[3] == m) wl[3] = NEG_INF;
                else if (wl[4] == m) wl[4] = NEG_INF;
                else if (wl[5] == m) wl[5] = NEG_INF;
                else if (wl[6] == m) wl[6] = NEG_INF;
                else                 wl[7] = NEG_INF;
            }
        }
    }

    bool defer = false;
    if ((thr - v9) < RISK_DELTA) {
        int pos = 0;
        if (gl == 0) pos = atomicAdd(wcnt, 1);
        pos = __shfl(pos, lane & 32, 64);   // broadcast from group leader
        if (pos < WCAP) {
            if (gl == 0) wlist[pos] = row;
            defer = true;
        }
    }
    if (!defer) {
        float p[8], psum = 0.f, pmu = 0.f;
        #pragma unroll
        for (int j = 0; j < 8; ++j) {
            p[j] = (lg[j] >= thr) ? __expf(lg[j] - mx) : 0.f;
            psum += p[j];
            pmu = fmaf(p[j], xlag[j], pmu);
        }
        psum += __shfl_xor(psum, 1, 64);   pmu += __shfl_xor(pmu, 1, 64);
        psum += __shfl_xor(psum, 2, 64);   pmu += __shfl_xor(pmu, 2, 64);
        psum += __shfl_xor(psum, 4, 64);   pmu += __shfl_xor(pmu, 4, 64);
        psum += __shfl_xor(psum, 8, 64);   pmu += __shfl_xor(pmu, 8, 64);
        psum += __shfl_xor(psum, 16, 64);  pmu += __shfl_xor(pmu, 16, 64);
        float inv = 1.f / psum;
        float4 woA = make_float4(p[0] * inv, p[1] * inv, p[2] * inv, p[3] * inv);
        float4 woB = make_float4(p[4] * inv, p[5] * inv, p[6] * inv, p[7] * inv);
        *reinterpret_cast<float4*>(&wOut[(size_t)row * LQ + l0]) = woA;
        *reinterpret_cast<float4*>(&wOut[(size_t)row * LQ + 128 + l0]) = woB;
        if (gl == 0) muOut[row] = fmaf(pmu, inv, bias);
    }
}

// ---------------- fixer: np-faithful fp32 pipeline, ONE ROW PER BLOCK --------------
// Per-dot arithmetic bit-identical to the proven arbiter-matcher (sequential f32 FMA,
// ascending index; __fadd_rn/__fmul_rn at materialization points). r9's unroll-1 +
// 2-deep dbuf discipline keeps VGPRs low (r8's spill pathology avoided); one row per
// block gives ~740 concurrent blocks so stage latency overlaps across CUs.
__global__ __launch_bounds__(256) void fixer(
    const float* __restrict__ x, const float* __restrict__ wk,
    const float* __restrict__ val_w, const float* __restrict__ conv_b,
    const float* __restrict__ ctx_b, const float* __restrict__ bias_w,
    const float* __restrict__ bias_b,
    const float* __restrict__ ctx_wT, const float* __restrict__ wqT,
    const float* __restrict__ conv_wT, const float* __restrict__ baseT,
    const int* __restrict__ wcnt, const int* __restrict__ wlist,
    float* __restrict__ muOut, float* __restrict__ wOut) {
    __shared__ float sxw[KCQ];
    __shared__ float sctxc[D];
    __shared__ float sctxp[D];
    __shared__ float sq[D];
    __shared__ float sqk[D];
    __shared__ float ssv1, sbd1;
    __shared__ float slog[LQ];

    int cnt = *wcnt;
    if (cnt > WCAP) cnt = WCAP;
    int tid = threadIdx.x;

    for (int ri = blockIdx.x; ri < cnt; ri += gridDim.x) {
        int row = wlist[ri];
        int b = row >> 12, t = row & (TQ - 1);
        const float* xb = x + b * TQ;
        if (tid < KCQ) {
            int ii = t - 8 + tid;
            sxw[tid] = (ii >= 0) ? xb[ii] : 0.f;
        }
        __syncthreads();

        // stage 1: causal conv (9 taps, ascending k) + conv_b
        if (tid < D) {
            float cw[KCQ];
            #pragma unroll
            for (int k = 0; k < KCQ; ++k) cw[k] = conv_wT[k * D + tid];
            float a = 0.f;
            #pragma unroll
            for (int k = 0; k < KCQ; ++k) a = fmaf(cw[k], sxw[k], a);
            sctxc[tid] = __fadd_rn(a, conv_b[tid]);
        }
        __syncthreads();

        // stage 2: ctx_proj — sequential FMA over d2, dbuf 16-batches
        if (tid < D) {
            float a = 0.f;
            float wv0[16], wv1[16];
            #pragma unroll
            for (int u = 0; u < 16; ++u) wv0[u] = ctx_wT[u * D + tid];
            #pragma unroll 1
            for (int d2 = 0; d2 < D; d2 += 32) {
                #pragma unroll
                for (int u = 0; u < 16; ++u) wv1[u] = ctx_wT[(d2 + 16 + u) * D + tid];
                #pragma unroll
                for (int u = 0; u < 16; ++u) a = fmaf(wv0[u], sctxc[d2 + u], a);
                if (d2 + 32 < D) {
                    #pragma unroll
                    for (int u = 0; u < 16; ++u) wv0[u] = ctx_wT[(d2 + 32 + u) * D + tid];
                }
                #pragma unroll
                for (int u = 0; u < 16; ++u) a = fmaf(wv1[u], sctxc[d2 + 16 + u], a);
            }
            sctxp[tid] = __fadd_rn(a, ctx_b[tid]);
        }
        __syncthreads();

        // stage 3: q = ctx @ wq.T ; sbd on idle thread 128
        if (tid < D) {
            float a = 0.f;
            float wv0[16], wv1[16];
            #pragma unroll
            for (int u = 0; u < 16; ++u) wv0[u] = wqT[u * D + tid];
            #pragma unroll 1
            for (int e2 = 0; e2 < D; e2 += 32) {
                #pragma unroll
                for (int u = 0; u < 16; ++u) wv1[u] = wqT[(e2 + 16 + u) * D + tid];
                #pragma unroll
                for (int u = 0; u < 16; ++u) a = fmaf(wv0[u], sctxp[e2 + u], a);
                if (e2 + 32 < D) {
                    #pragma unroll
                    for (int u = 0; u < 16; ++u) wv0[u] = wqT[(e2 + 32 + u) * D + tid];
                }
                #pragma unroll
                for (int u = 0; u < 16; ++u) a = fmaf(wv1[u], sctxp[e2 + 16 + u], a);
            }
            sq[tid] = a;
        } else if (tid == D) {
            float a = 0.f;
            #pragma unroll 1
            for (int e2 = 0; e2 < D; ++e2) a = fmaf(sctxp[e2], bias_w[e2], a);
            sbd1 = a;
        }
        __syncthreads();

        // stage 4: qk = q @ wk
        if (tid < D) {
            float a = 0.f;
            float wv0[16], wv1[16];
            #pragma unroll
            for (int u = 0; u < 16; ++u) wv0[u] = wk[u * D + tid];
            #pragma unroll 1
            for (int a2i = 0; a2i < D; a2i += 32) {
                #pragma unroll
                for (int u = 0; u < 16; ++u) wv1[u] = wk[(a2i + 16 + u) * D + tid];
                #pragma unroll
                for (int u = 0; u < 16; ++u) a = fmaf(wv0[u], sq[a2i + u], a);
                if (a2i + 32 < D) {
                    #pragma unroll
                    for (int u = 0; u < 16; ++u) wv0[u] = wk[(a2i + 32 + u) * D + tid];
                }
                #pragma unroll
                for (int u = 0; u < 16; ++u) a = fmaf(wv1[u], sq[a2i + 16 + u], a);
            }
            sqk[tid] = a;
        }
        __syncthreads();

        // stage 4.5: ssv on thread 0 (sequential, proven order);
        // all threads prefetch their first baseT batch meanwhile (independent of sqk)
        float bd0[16];
        #pragma unroll
        for (int u = 0; u < 16; ++u) bd0[u] = baseT[u * LQ + tid];
        if (tid == 0) {
            float a = 0.f;
            #pragma unroll 1
            for (int d2 = 0; d2 < D; ++d2) a = fmaf(sqk[d2], val_w[d2], a);
            ssv1 = a;
        }
        __syncthreads();

        // logits: blog[l=tid] = sequential FMA over d2 (dbuf), then combine with xlag
        {
            int l = tid;
            float c0 = 0.f;
            float bd1[16];
            #pragma unroll 1
            for (int d2 = 0; d2 < D; d2 += 32) {
                #pragma unroll
                for (int u = 0; u < 16; ++u) bd1[u] = baseT[(d2 + 16 + u) * LQ + l];
                #pragma unroll
                for (int u = 0; u < 16; ++u) c0 = fmaf(bd0[u], sqk[d2 + u], c0);
                if (d2 + 32 < D) {
                    #pragma unroll
                    for (int u = 0; u < 16; ++u) bd0[u] = baseT[(d2 + 32 + u) * LQ + l];
                }
                #pragma unroll
                for (int u = 0; u < 16; ++u) c0 = fmaf(bd1[u], sqk[d2 + 16 + u], c0);
            }
            int ii = t - 1 - l;
            float xl = (ii >= 0) ? xb[ii] : 0.f;
            slog[l] = __fadd_rn(__fmul_rn(xl, ssv1), c0);
        }
        __syncthreads();

        // wave 0: f32 top-8 + f32 softmax + writes (identical ladder/semantics)
        if (tid < 64) {
            int lane = tid;
            float lv0 = slog[lane], lv1 = slog[lane + 64];
            float lv2 = slog[lane + 128], lv3 = slog[lane + 192];
            const float NEG_INF = -__builtin_inff();
            float w0 = lv0, w1 = lv1, w2 = lv2, w3 = lv3;
            float mx = 0.f, thr = 0.f;
            #pragma unroll
            for (int it = 0; it < 8; ++it) {
                float lm = fmaxf(fmaxf(w0, w1), fmaxf(w2, w3));
                float m = lm;
                #pragma unroll
                for (int off = 32; off >= 1; off >>= 1)
                    m = fmaxf(m, __shfl_xor(m, off, 64));
                if (it == 0) mx = m;
                thr = m;
                if (it < 7) {
                    unsigned long long ball = __ballot(lm == m);
                    int leader = __ffsll(ball) - 1;
                    if (lane == leader) {
                        if (w0 == m)      w0 = NEG_INF;
                        else if (w1 == m) w1 = NEG_INF;
                        else if (w2 == m) w2 = NEG_INF;
                        else              w3 = NEG_INF;
                    }
                }
            }
            float p[4], xlg[4];
            double ps = 0.0;
            float lvs[4] = {lv0, lv1, lv2, lv3};
            #pragma unroll
            for (int j = 0; j < 4; ++j) {
                int l = lane + 64 * j;
                int ii = t - 1 - l;
                xlg[j] = (ii >= 0) ? xb[ii] : 0.f;
                p[j] = (lvs[j] >= thr) ? (float)exp((double)__fsub_rn(lvs[j], mx)) : 0.f;
                ps += (double)p[j];
            }
            #pragma unroll
            for (int off = 32; off >= 1; off >>= 1)
                ps += __shfl_xor(ps, off, 64);
            float psf = (float)ps;
            double mud = 0.0;
            #pragma unroll
            for (int j = 0; j < 4; ++j) {
                float wv = __fdiv_rn(p[j], psf);
                wOut[(size_t)row * LQ + lane + 64 * j] = wv;
                mud += (double)__fmul_rn(wv, xlg[j]);
            }
            #pragma unroll
            for (int off = 32; off >= 1; off >>= 1)
                mud += __shfl_xor(mud, off, 64);
            if (lane == 0) {
                float m1 = (float)mud;
                m1 = __fadd_rn(m1, sbd1);
                m1 = __fadd_rn(m1, bias_b[0]);
                muOut[row] = m1;
            }
        }
        __syncthreads();
    }
}

extern "C" void kernel_launch(void* const* d_in, const int* in_sizes, int n_in,
                              void* d_out, int out_size, void* d_ws, size_t ws_size,
                              hipStream_t stream) {
    const float* x         = (const float*)d_in[0];
    const float* lag_embed = (const float*)d_in[1];
    const float* val_w     = (const float*)d_in[2];
    const float* val_b     = (const float*)d_in[3];
    const float* conv_w    = (const float*)d_in[4];
    const float* conv_b    = (const float*)d_in[5];
    const float* ctx_w     = (const float*)d_in[6];
    const float* ctx_b     = (const float*)d_in[7];
    const float* wq        = (const float*)d_in[8];
    const float* wk        = (const float*)d_in[9];
    const float* bias_w    = (const float*)d_in[10];
    const float* bias_b    = (const float*)d_in[11];

    char* wsb = (char*)d_ws;
    double* T2  = (double*)wsb;     // 16384 d
    double* g   = T2 + 16384;       // 1152
    double* u   = g + 1152;         // 128
    double* c1  = u + 128;          // 128
    double* gbT = c1 + 128;         // 2304
    double* cbv = gbT + 2304;       // 256
    double* cst = cbv + 256;        // 20
    int* wcnt  = (int*)(wsb + 163840);
    int* wlist = wcnt + 1;          // WCAP=16384 ints
    float* ctx_wT  = (float*)(wsb + 229504);   // 16384 f
    float* wqT     = ctx_wT + 16384;           // 16384 f
    float* conv_wT = wqT + 16384;              // 1152 f
    float* baseT   = conv_wT + 1152;           // 32768 f

    float* muOut = (float*)d_out;
    float* wOut  = muOut + BQ * TQ;

    hipLaunchKernelGGL(pk1, dim3(D + 2), dim3(256), 0, stream,
                       wk, wq, ctx_w, bias_w, conv_w, val_b, lag_embed,
                       T2, u, wcnt, ctx_wT, wqT, conv_wT, baseT);
    hipLaunchKernelGGL(pk2, dim3(D), dim3(D), 0, stream, T2, ctx_w, conv_w, conv_b, ctx_b, g, c1);
    hipLaunchKernelGGL(pk3, dim3(LQ + 1), dim3(D), 0, stream,
                       lag_embed, val_b, val_w, conv_w, conv_b, ctx_b, bias_w, bias_b,
                       g, c1, u, gbT, cbv, cst);
    hipLaunchKernelGGL(lag_main, dim3(BQ * TQ / 8), dim3(256), 0, stream,
                       x, gbT, cbv, cst, muOut, wOut, wcnt, wlist);
    hipLaunchKernelGGL(fixer, dim3(1024), dim3(256), 0, stream,
                       x, wk, val_w, conv_b, ctx_b, bias_w, bias_b,
                       ctx_wT, wqT, conv_wT, baseT, wcnt, wlist, muOut, wOut);
}